// Round 5
// baseline (1069.218 us; speedup 1.0000x reference)
//
#include <hip/hip_runtime.h>
#include <hip/hip_bf16.h>
#include <math.h>

// ---------------------------------------------------------------------------
// GCN classifier pipeline, split-bf16 MFMA GEMMs, blob-staged A.
// All GEMMs are K=128 x FO=128 (L3 = two column halves, L4 = two K halves
// with accumulate). 3 rotating 51MB buffers keep ws under ~170 MB.
//   L1: t = x @ Wg1         ; a = agg(t) ; stats(a)   (biases cancel in BN)
//   L2: t = bnrelu(a) @ Wg2 ; a = agg(t) ; stats(a)
//   L3: th = bnrelu(a) @ Wm1[:,h*128:+128], per-half stats + split
//   L4: c4 = sum_h bnrelu(th) @ Wm2[h*128:+128,:] ; stats(c4)
//   out = sigmoid( dot(bnrelu(c4), Wo) + bo )
// ---------------------------------------------------------------------------

typedef __attribute__((ext_vector_type(8))) short bf16x8;
typedef __attribute__((ext_vector_type(4))) float f32x4;

// trunc-hi + rne-lo split: residual ~2^-17 relative
__device__ inline void split2(float x, ushort& h, ushort& l) {
    unsigned u = __float_as_uint(x);
    h = (ushort)(u >> 16);
    float hb = __uint_as_float(u & 0xFFFF0000u);
    float lo = x - hb;
    unsigned b = __float_as_uint(lo);
    l = (ushort)((b + 0x7FFFu + ((b >> 16) & 1u)) >> 16);
}

__device__ inline void gload_lds16(const void* g, void* l) {
#if defined(__HIP_DEVICE_COMPILE__)
    __builtin_amdgcn_global_load_lds(
        (const __attribute__((address_space(1))) unsigned int*)g,
        (__attribute__((address_space(3))) unsigned int*)l, 16, 0, 0);
#endif
}

// ---------------- CSR build ----------------
__global__ void degree_kernel(const int* __restrict__ dst, int* __restrict__ deg, int E) {
    int i = blockIdx.x * blockDim.x + threadIdx.x;
    if (i < E) atomicAdd(&deg[dst[i]], 1);
}

__global__ void dinv_kernel(const int* __restrict__ deg, float* __restrict__ dinv, int N) {
    int i = blockIdx.x * blockDim.x + threadIdx.x;
    if (i < N) dinv[i] = rsqrtf((float)(deg[i] + 1));
}

__global__ void blocksum_kernel(const int* __restrict__ deg, int* __restrict__ bsum, int N) {
    __shared__ int sh[256];
    int tid = threadIdx.x;
    int base = blockIdx.x * 1024 + tid * 4;
    int s = 0;
    #pragma unroll
    for (int j = 0; j < 4; ++j) { int idx = base + j; if (idx < N) s += deg[idx]; }
    sh[tid] = s; __syncthreads();
    for (int off = 128; off > 0; off >>= 1) {
        if (tid < off) sh[tid] += sh[tid + off];
        __syncthreads();
    }
    if (tid == 0) bsum[blockIdx.x] = sh[0];
}

__global__ void scan_bsum_kernel(int* bsum, int nb) {
    if (threadIdx.x == 0 && blockIdx.x == 0) {
        int run = 0;
        for (int i = 0; i < nb; ++i) { int v = bsum[i]; bsum[i] = run; run += v; }
    }
}

__global__ void scanwrite_kernel(const int* __restrict__ deg, const int* __restrict__ bsumex,
                                 int* __restrict__ row_ptr, int* __restrict__ cursor,
                                 int N, int Etot) {
    __shared__ int sh[256];
    int tid = threadIdx.x;
    int base = blockIdx.x * 1024 + tid * 4;
    int v[4]; int tsum = 0;
    #pragma unroll
    for (int j = 0; j < 4; ++j) { int idx = base + j; v[j] = (idx < N) ? deg[idx] : 0; tsum += v[j]; }
    sh[tid] = tsum; __syncthreads();
    for (int off = 1; off < 256; off <<= 1) {
        int x = (tid >= off) ? sh[tid - off] : 0;
        __syncthreads();
        sh[tid] += x;
        __syncthreads();
    }
    int run = sh[tid] - tsum + bsumex[blockIdx.x];
    #pragma unroll
    for (int j = 0; j < 4; ++j) {
        int idx = base + j;
        if (idx < N) { row_ptr[idx] = run; cursor[idx] = run; }
        run += v[j];
    }
    if (blockIdx.x == 0 && tid == 0) row_ptr[N] = Etot;
}

// store (src, dinv[src]) per edge, CSR-ordered by dst
__global__ void scatter_kernel(const int* __restrict__ src, const int* __restrict__ dst,
                               const float* __restrict__ dinv,
                               int* __restrict__ cursor, uint2* __restrict__ esw, int E) {
    int i = blockIdx.x * blockDim.x + threadIdx.x;
    if (i < E) {
        int d = dst[i];
        int s = src[i];
        int pos = atomicAdd(&cursor[d], 1);
        esw[pos] = make_uint2((unsigned)s, __float_as_uint(dinv[s]));
    }
}

// ---------------- W pre-split into fragment-native layout (K=128) ----------
// W2[cb][kg][ci][j] = split(W[kg*8+j][cb*128+ci]), flat = ((cb*16+kg)*128+ci)*8+j
__global__ void wsplit_kernel(const float* __restrict__ W, ushort* __restrict__ Wh,
                              ushort* __restrict__ Wl, int FO) {
    int t = blockIdx.x * 256 + threadIdx.x;
    if (t >= 128 * FO) return;
    int j   = t & 7;
    int ci  = (t >> 3) & 127;
    int rest = t >> 10;
    int kg  = rest & 15;
    int cb  = rest >> 4;
    float w = W[(size_t)(kg * 8 + j) * FO + cb * 128 + ci];
    ushort h, l; split2(w, h, l);
    Wh[t] = h; Wl[t] = l;
}

// ---------------- actsplit: X(N x 128) -> bnrelu -> split -> blob ----------
// Blob per (rowtile 128 x ktile 32): 16384 B = [h: 4 planes x 2048B][l: same]
// plane: [row 128][16B = 8 bf16 (j)].  4 ktiles per rowtile (K=128).
template<bool ACT>
__global__ __launch_bounds__(256)
void actsplit_kernel(const float* __restrict__ X, char* __restrict__ A2,
                     const float* __restrict__ scale, const float* __restrict__ shift,
                     int nrows)
{
    int t = blockIdx.x * 256 + threadIdx.x;
    int r = t & 127;
    int kg = (t >> 7) & 3;
    int kstep = (t >> 9) & 3;
    int rowtile = t >> 11;
    int gr = rowtile * 128 + r;
    int k = kstep * 32 + kg * 8;
    float4 v0 = make_float4(0.f, 0.f, 0.f, 0.f), v1 = v0;
    if (gr < nrows) {
        v0 = *(const float4*)&X[(size_t)gr * 128 + k];
        v1 = *(const float4*)&X[(size_t)gr * 128 + k + 4];
        if (ACT) {
            float4 sc0 = *(const float4*)&scale[k],     sf0 = *(const float4*)&shift[k];
            float4 sc1 = *(const float4*)&scale[k + 4], sf1 = *(const float4*)&shift[k + 4];
            v0.x = fmaxf(fmaf(v0.x, sc0.x, sf0.x), 0.f);
            v0.y = fmaxf(fmaf(v0.y, sc0.y, sf0.y), 0.f);
            v0.z = fmaxf(fmaf(v0.z, sc0.z, sf0.z), 0.f);
            v0.w = fmaxf(fmaf(v0.w, sc0.w, sf0.w), 0.f);
            v1.x = fmaxf(fmaf(v1.x, sc1.x, sf1.x), 0.f);
            v1.y = fmaxf(fmaf(v1.y, sc1.y, sf1.y), 0.f);
            v1.z = fmaxf(fmaf(v1.z, sc1.z, sf1.z), 0.f);
            v1.w = fmaxf(fmaf(v1.w, sc1.w, sf1.w), 0.f);
        }
    }
    union { uint4 u; ushort s[8]; } ph, pl;
    split2(v0.x, ph.s[0], pl.s[0]); split2(v0.y, ph.s[1], pl.s[1]);
    split2(v0.z, ph.s[2], pl.s[2]); split2(v0.w, ph.s[3], pl.s[3]);
    split2(v1.x, ph.s[4], pl.s[4]); split2(v1.y, ph.s[5], pl.s[5]);
    split2(v1.z, ph.s[6], pl.s[6]); split2(v1.w, ph.s[7], pl.s[7]);
    char* base = A2 + ((size_t)(rowtile * 4 + kstep) * 16384) + kg * 2048 + r * 16;
    *(uint4*)base          = ph.u;
    *(uint4*)(base + 8192) = pl.u;
}

// ---------------- GEMM: C[nrows][128] (+)= A2blob @ W2[cbW] ----------------
// K=128. 128x128 block, 4 waves (2x2), 64x64/wave, mfma 16x16x32 bf16 x3.
template<bool ACC>
__global__ __launch_bounds__(256)
void gemm_mfma_kernel(const char* __restrict__ A2, const ushort* __restrict__ W2h,
                      const ushort* __restrict__ W2l, float* __restrict__ C,
                      int nrows, int cbW)
{
    __shared__ char lds[16384];
    const int tid  = threadIdx.x;
    const int lane = tid & 63;
    const int wid  = tid >> 6;
    const int wm   = wid & 1, wn = wid >> 1;
    const int row0 = blockIdx.x * 128;
    const int l15  = lane & 15;
    const int l4   = lane >> 4;

    f32x4 zero = {0.f, 0.f, 0.f, 0.f};
    f32x4 acc[4][4];
    #pragma unroll
    for (int m = 0; m < 4; ++m)
        #pragma unroll
        for (int n = 0; n < 4; ++n) acc[m][n] = zero;

    const char* blob = A2 + ((size_t)blockIdx.x * 4) * 16384;

    for (int kstep = 0; kstep < 4; ++kstep) {
        const char* src = blob + (size_t)kstep * 16384;
        #pragma unroll
        for (int p = 0; p < 4; ++p) {
            gload_lds16(src + (((p * 4 + wid) * 64 + lane) * 16), &lds[(p * 4 + wid) * 1024]);
        }
        bf16x8 bh[4], bl[4];
        #pragma unroll
        for (int n = 0; n < 4; ++n) {
            int ci = wn * 64 + n * 16 + l15;
            size_t off = (((size_t)(cbW * 16 + kstep * 4 + l4)) * 128 + ci) * 8;
            bh[n] = *(const bf16x8*)&W2h[off];
            bl[n] = *(const bf16x8*)&W2l[off];
        }
        __syncthreads();
        bf16x8 ah[4], al[4];
        #pragma unroll
        for (int m = 0; m < 4; ++m) {
            int o = l4 * 2048 + (wm * 64 + m * 16 + l15) * 16;
            ah[m] = *(const bf16x8*)&lds[o];
            al[m] = *(const bf16x8*)&lds[o + 8192];
        }
        #pragma unroll
        for (int m = 0; m < 4; ++m)
            #pragma unroll
            for (int n = 0; n < 4; ++n) {
                acc[m][n] = __builtin_amdgcn_mfma_f32_16x16x32_bf16(ah[m], bh[n], acc[m][n], 0, 0, 0);
                acc[m][n] = __builtin_amdgcn_mfma_f32_16x16x32_bf16(ah[m], bl[n], acc[m][n], 0, 0, 0);
                acc[m][n] = __builtin_amdgcn_mfma_f32_16x16x32_bf16(al[m], bh[n], acc[m][n], 0, 0, 0);
            }
        __syncthreads();
    }

    // epilogue: row = (lane>>4)*4 + reg, col = lane&15 within fragment
    #pragma unroll
    for (int m = 0; m < 4; ++m) {
        int rbase = row0 + wm * 64 + m * 16 + l4 * 4;
        #pragma unroll
        for (int r = 0; r < 4; ++r) {
            int gr = rbase + r;
            if (gr < nrows) {
                #pragma unroll
                for (int n = 0; n < 4; ++n) {
                    int gc = wn * 64 + n * 16 + l15;
                    size_t idx = (size_t)gr * 128 + gc;
                    if (ACC) C[idx] += acc[m][n][r];
                    else     C[idx]  = acc[m][n][r];
                }
            }
        }
    }
}

// ---------------- edge aggregation (CSR, wave/node, uniform payload reads) ----
// A[i] = dinv[i] * sum_e w_e * T[src_e] + dinv[i]^2 * T[i],  w_e = dinv[src_e]
__global__ void agg_kernel(const float* __restrict__ T, float* __restrict__ Aout,
                           const float* __restrict__ dinv,
                           const int* __restrict__ row_ptr, const uint2* __restrict__ esw,
                           int nrows)
{
    int gw = (blockIdx.x * blockDim.x + threadIdx.x) >> 6;
    int lane = threadIdx.x & 63;
    int nw = (gridDim.x * blockDim.x) >> 6;
    int c = lane * 2;
    for (int i = gw; i < nrows; i += nw) {
        float di = dinv[i];
        int e0 = __builtin_amdgcn_readfirstlane(row_ptr[i]);
        int e1 = __builtin_amdgcn_readfirstlane(row_ptr[i + 1]);
        float ax0 = 0.f, ay0 = 0.f, ax1 = 0.f, ay1 = 0.f;
        int e = e0;
        int eq = e0 + ((e1 - e0) & ~3);
        for (; e < eq; e += 4) {
            uint2 p0 = esw[e],     p1 = esw[e + 1];
            uint2 p2 = esw[e + 2], p3 = esw[e + 3];
            float2 v0 = *(const float2*)&T[((size_t)p0.x << 7) + c];
            float2 v1 = *(const float2*)&T[((size_t)p1.x << 7) + c];
            float2 v2 = *(const float2*)&T[((size_t)p2.x << 7) + c];
            float2 v3 = *(const float2*)&T[((size_t)p3.x << 7) + c];
            float w0 = __uint_as_float(p0.y), w1 = __uint_as_float(p1.y);
            float w2 = __uint_as_float(p2.y), w3 = __uint_as_float(p3.y);
            ax0 = fmaf(w0, v0.x, ax0); ay0 = fmaf(w0, v0.y, ay0);
            ax1 = fmaf(w1, v1.x, ax1); ay1 = fmaf(w1, v1.y, ay1);
            ax0 = fmaf(w2, v2.x, ax0); ay0 = fmaf(w2, v2.y, ay0);
            ax1 = fmaf(w3, v3.x, ax1); ay1 = fmaf(w3, v3.y, ay1);
        }
        for (; e < e1; ++e) {
            uint2 p = esw[e];
            float w = __uint_as_float(p.y);
            float2 v = *(const float2*)&T[((size_t)p.x << 7) + c];
            ax0 = fmaf(w, v.x, ax0); ay0 = fmaf(w, v.y, ay0);
        }
        float ax = ax0 + ax1, ay = ay0 + ay1;
        float2 self = *(const float2*)&T[((size_t)i << 7) + c];
        float2 o;
        o.x = fmaf(di, ax, di * di * self.x);
        o.y = fmaf(di, ay, di * di * self.y);
        *(float2*)&Aout[((size_t)i << 7) + c] = o;
    }
}

// ---------------- per-column sum / sumsq (F=128) ----------------
__global__ void colstats_kernel(const float* __restrict__ X, int nrows, int rpb,
                                float* __restrict__ colsum, float* __restrict__ colsq)
{
    __shared__ float ss[256], sq[256];
    int tid = threadIdx.x;
    int c = tid & 127;
    int roff = tid >> 7;
    int r0 = blockIdx.x * rpb;
    int r1 = min(nrows, r0 + rpb);
    float s = 0.f, q = 0.f;
    for (int r = r0 + roff; r < r1; r += 2) {
        float v = X[(size_t)r * 128 + c];
        s += v; q += v * v;
    }
    ss[tid] = s; sq[tid] = q;
    __syncthreads();
    if (tid < 128) {
        float S = ss[tid] + ss[tid + 128];
        float Q = sq[tid] + sq[tid + 128];
        atomicAdd(&colsum[tid], S);
        atomicAdd(&colsq[tid], Q);
    }
}

__global__ void bnparam_kernel(const float* __restrict__ colsum, const float* __restrict__ colsq,
                               const float* __restrict__ g, const float* __restrict__ be,
                               float* __restrict__ scale, float* __restrict__ shift,
                               float invN)
{
    int c = threadIdx.x;
    if (c < 128) {
        float mean = colsum[c] * invN;
        float var = colsq[c] * invN - mean * mean;
        float rs = rsqrtf(var + 1e-5f);
        float sc = g[c] * rs;
        scale[c] = sc;
        shift[c] = be[c] - mean * sc;
    }
}

// ---------------- final: sigmoid( dot(bnrelu(A[i]), Wo) + bo ) ----------------
__global__ void final_kernel(const float* __restrict__ A, const float* __restrict__ Wo,
                             const float* __restrict__ bo,
                             const float* __restrict__ scale, const float* __restrict__ shift,
                             float* __restrict__ out, int nrows)
{
    int gw = (blockIdx.x * blockDim.x + threadIdx.x) >> 6;
    int lane = threadIdx.x & 63;
    int nw = (gridDim.x * blockDim.x) >> 6;
    int c = lane * 2;
    float2 w = *(const float2*)&Wo[c];
    float2 sc = *(const float2*)&scale[c];
    float2 sf = *(const float2*)&shift[c];
    float bias = bo[0];
    for (int i = gw; i < nrows; i += nw) {
        float2 v = *(const float2*)&A[(size_t)i * 128 + c];
        float x = fmaxf(fmaf(v.x, sc.x, sf.x), 0.f) * w.x
                + fmaxf(fmaf(v.y, sc.y, sf.y), 0.f) * w.y;
        #pragma unroll
        for (int off = 32; off > 0; off >>= 1) x += __shfl_down(x, off);
        if (lane == 0) out[i] = 1.f / (1.f + expf(-(x + bias)));
    }
}

extern "C" void kernel_launch(void* const* d_in, const int* in_sizes, int n_in,
                              void* d_out, int out_size, void* d_ws, size_t ws_size,
                              hipStream_t stream)
{
    const float* x   = (const float*)d_in[0];
    const int* ei    = (const int*)d_in[1];
    const float* Wg1 = (const float*)d_in[2];
    const float* g1  = (const float*)d_in[4];
    const float* be1 = (const float*)d_in[5];
    const float* Wg2 = (const float*)d_in[6];
    const float* g2  = (const float*)d_in[8];
    const float* be2 = (const float*)d_in[9];
    const float* Wm1 = (const float*)d_in[10];
    const float* g3  = (const float*)d_in[12];
    const float* be3 = (const float*)d_in[13];
    const float* Wm2 = (const float*)d_in[14];
    const float* g4  = (const float*)d_in[16];
    const float* be4 = (const float*)d_in[17];
    const float* Wo  = (const float*)d_in[18];
    const float* bo  = (const float*)d_in[19];

    const int N = in_sizes[0] / 128;
    const int E = in_sizes[1] / 2;
    const int* srcv = ei;
    const int* dstv = ei + E;
    const int rowtiles = (N + 127) / 128;
    const size_t blobsz = (size_t)rowtiles * 4 * 16384;   // K=128 blob (51.25 MB)

    char* p = (char*)d_ws;
    auto alloc = [&](size_t bytes) { void* r = (void*)p; p += (bytes + 255) & ~(size_t)255; return r; };
    float* buf1    = (float*)alloc((size_t)N * 128 * 4);  // GEMM outputs
    char*  buf2    = (char*)alloc(blobsz);                // Abuf (f32 N*128) / L4-input blob
    char*  buf3    = (char*)alloc(blobsz);                // L1-L3 input blob / final activations
    int*   deg     = (int*)alloc((size_t)N * 4);
    float* dinv    = (float*)alloc((size_t)N * 4);
    int*   row_ptr = (int*)alloc((size_t)(N + 1) * 4);
    int*   cursor  = (int*)alloc((size_t)N * 4);
    uint2* esw     = (uint2*)alloc((size_t)(E + 8) * 8);
    int*   bsum    = (int*)alloc(4096);
    float* colsum  = (float*)alloc(512 * 4);              // [0:128)=sum, [128:256)=sumsq
    float* colsq   = colsum + 128;
    float* scale   = (float*)alloc(256 * 4);
    float* shift   = (float*)alloc(256 * 4);
    ushort* W2h    = (ushort*)alloc(32768 * 2);
    ushort* W2l    = (ushort*)alloc(32768 * 2);

    float* Abuf = (float*)buf2;
    float* C4   = (float*)buf3;
    const int rpb = (N + 255) / 256;
    const float invN = 1.f / (float)N;
    const int as_blocks = rowtiles * 8;   // actsplit: rowtiles*2048 threads

    // --- CSR build ---
    (void)hipMemsetAsync(deg, 0, (size_t)N * 4, stream);
    degree_kernel<<<(E + 255) / 256, 256, 0, stream>>>(dstv, deg, E);
    dinv_kernel<<<(N + 255) / 256, 256, 0, stream>>>(deg, dinv, N);
    int nb = (N + 1023) / 1024;
    blocksum_kernel<<<nb, 256, 0, stream>>>(deg, bsum, N);
    scan_bsum_kernel<<<1, 64, 0, stream>>>(bsum, nb);
    scanwrite_kernel<<<nb, 256, 0, stream>>>(deg, bsum, row_ptr, cursor, N, E);
    scatter_kernel<<<(E + 255) / 256, 256, 0, stream>>>(srcv, dstv, dinv, cursor, esw, E);

    dim3 gg(rowtiles, 1);

    // --- L1: GCNConv 1 (x @ Wg1) ---
    wsplit_kernel<<<64, 256, 0, stream>>>(Wg1, W2h, W2l, 128);
    actsplit_kernel<false><<<as_blocks, 256, 0, stream>>>(x, buf3, nullptr, nullptr, N);
    gemm_mfma_kernel<false><<<gg, 256, 0, stream>>>(buf3, W2h, W2l, buf1, N, 0);
    agg_kernel<<<2048, 256, 0, stream>>>(buf1, Abuf, dinv, row_ptr, esw, N);
    (void)hipMemsetAsync(colsum, 0, 256 * 4, stream);
    colstats_kernel<<<256, 256, 0, stream>>>(Abuf, N, rpb, colsum, colsq);
    bnparam_kernel<<<1, 128, 0, stream>>>(colsum, colsq, g1, be1, scale, shift, invN);

    // --- L2: GCNConv 2 ---
    wsplit_kernel<<<64, 256, 0, stream>>>(Wg2, W2h, W2l, 128);
    actsplit_kernel<true><<<as_blocks, 256, 0, stream>>>(Abuf, buf3, scale, shift, N);
    gemm_mfma_kernel<false><<<gg, 256, 0, stream>>>(buf3, W2h, W2l, buf1, N, 0);
    agg_kernel<<<2048, 256, 0, stream>>>(buf1, Abuf, dinv, row_ptr, esw, N);
    (void)hipMemsetAsync(colsum, 0, 256 * 4, stream);
    colstats_kernel<<<256, 256, 0, stream>>>(Abuf, N, rpb, colsum, colsq);
    bnparam_kernel<<<1, 128, 0, stream>>>(colsum, colsq, g2, be2, scale, shift, invN);

    // --- L3 (two column halves) + L4 (two K halves, accumulate) ---
    // L3 input blob -> buf3 (alive until both L3 halves done)
    actsplit_kernel<true><<<as_blocks, 256, 0, stream>>>(Abuf, buf3, scale, shift, N);
    wsplit_kernel<<<128, 256, 0, stream>>>(Wm1, W2h, W2l, 256);

    // h0: L3 half 0 -> buf1; stats; split -> buf2 (L4h0 blob)
    gemm_mfma_kernel<false><<<gg, 256, 0, stream>>>(buf3, W2h, W2l, buf1, N, 0);
    (void)hipMemsetAsync(colsum, 0, 256 * 4, stream);
    colstats_kernel<<<256, 256, 0, stream>>>(buf1, N, rpb, colsum, colsq);
    bnparam_kernel<<<1, 128, 0, stream>>>(colsum, colsq, g3, be3, scale, shift, invN);
    actsplit_kernel<true><<<as_blocks, 256, 0, stream>>>(buf1, buf2, scale, shift, N);

    // h1: L3 half 1 -> buf1 (buf3 blob last use)
    gemm_mfma_kernel<false><<<gg, 256, 0, stream>>>(buf3, W2h, W2l, buf1, N, 1);
    (void)hipMemsetAsync(colsum, 0, 256 * 4, stream);
    colstats_kernel<<<256, 256, 0, stream>>>(buf1, N, rpb, colsum, colsq);
    bnparam_kernel<<<1, 128, 0, stream>>>(colsum, colsq, g3 + 128, be3 + 128, scale, shift, invN);

    // L4 h0: C4(buf3) = blob(buf2) @ Wm2[0:128,:]
    wsplit_kernel<<<64, 256, 0, stream>>>(Wm2, W2h, W2l, 128);
    gemm_mfma_kernel<false><<<gg, 256, 0, stream>>>(buf2, W2h, W2l, C4, N, 0);

    // L4 h1: split L3h1 -> buf2; C4 += blob @ Wm2[128:256,:]
    actsplit_kernel<true><<<as_blocks, 256, 0, stream>>>(buf1, buf2, scale, shift, N);
    wsplit_kernel<<<64, 256, 0, stream>>>(Wm2 + 128 * 128, W2h, W2l, 128);
    gemm_mfma_kernel<true><<<gg, 256, 0, stream>>>(buf2, W2h, W2l, C4, N, 0);

    // --- BN4 + output ---
    (void)hipMemsetAsync(colsum, 0, 256 * 4, stream);
    colstats_kernel<<<256, 256, 0, stream>>>(C4, N, rpb, colsum, colsq);
    bnparam_kernel<<<1, 128, 0, stream>>>(colsum, colsq, g4, be4, scale, shift, invN);
    final_kernel<<<1024, 256, 0, stream>>>(C4, Wo, bo, scale, shift, (float*)d_out, N);
}

// Round 7
// 1059.756 us; speedup vs baseline: 1.0089x; 1.0089x over previous
//
#include <hip/hip_runtime.h>
#include <hip/hip_bf16.h>
#include <math.h>

// ---------------------------------------------------------------------------
// GCN classifier pipeline, split-bf16 MFMA GEMMs, blob-staged A (prefetch-all),
// fused column-stats (in agg + GEMM epilogues), BN params computed inline in
// consumers. 3 rotating 51MB buffers.
//   L1: t = x @ Wg1         ; a = agg(t)+stats(S1)
//   L2: t = bnrelu1(a)@Wg2  ; a = agg(t)+stats(S2)
//   L3: th = bnrelu2(a)@Wm1[:,h*128:+128]  (+stats S3a/S3b in epilogue)
//   L4: c4 = sum_h bnrelu3h(th)@Wm2[h*128:+128,:]  (+stats S4 on final ACC)
//   out = sigmoid( dot(bnrelu4(c4), Wo) + bo )
// ---------------------------------------------------------------------------

typedef __attribute__((ext_vector_type(8))) short bf16x8;
typedef __attribute__((ext_vector_type(4))) float f32x4;

// trunc-hi + rne-lo split: residual ~2^-17 relative
__device__ inline void split2(float x, ushort& h, ushort& l) {
    unsigned u = __float_as_uint(x);
    h = (ushort)(u >> 16);
    float hb = __uint_as_float(u & 0xFFFF0000u);
    float lo = x - hb;
    unsigned b = __float_as_uint(lo);
    l = (ushort)((b + 0x7FFFu + ((b >> 16) & 1u)) >> 16);
}

__device__ inline void gload_lds16(const void* g, void* l) {
#if defined(__HIP_DEVICE_COMPILE__)
    __builtin_amdgcn_global_load_lds(
        (const __attribute__((address_space(1))) unsigned int*)g,
        (__attribute__((address_space(3))) unsigned int*)l, 16, 0, 0);
#endif
}

// ---------------- CSR build ----------------
__global__ void degree_kernel(const int* __restrict__ dst, int* __restrict__ deg, int E) {
    int i = blockIdx.x * blockDim.x + threadIdx.x;
    if (i < E) atomicAdd(&deg[dst[i]], 1);
}

__global__ void blocksum_kernel(const int* __restrict__ deg, int* __restrict__ bsum, int N) {
    __shared__ int sh[256];
    int tid = threadIdx.x;
    int base = blockIdx.x * 1024 + tid * 4;
    int s = 0;
    #pragma unroll
    for (int j = 0; j < 4; ++j) { int idx = base + j; if (idx < N) s += deg[idx]; }
    sh[tid] = s; __syncthreads();
    for (int off = 128; off > 0; off >>= 1) {
        if (tid < off) sh[tid] += sh[tid + off];
        __syncthreads();
    }
    if (tid == 0) bsum[blockIdx.x] = sh[0];
}

__global__ void scan_bsum_kernel(int* bsum, int nb) {
    if (threadIdx.x == 0 && blockIdx.x == 0) {
        int run = 0;
        for (int i = 0; i < nb; ++i) { int v = bsum[i]; bsum[i] = run; run += v; }
    }
}

// exclusive scan of deg -> row_ptr/cursor; also dinv = rsqrt(deg+1)
__global__ void scanwrite_kernel(const int* __restrict__ deg, const int* __restrict__ bsumex,
                                 int* __restrict__ row_ptr, int* __restrict__ cursor,
                                 float* __restrict__ dinv, int N, int Etot) {
    __shared__ int sh[256];
    int tid = threadIdx.x;
    int base = blockIdx.x * 1024 + tid * 4;
    int v[4]; int tsum = 0;
    #pragma unroll
    for (int j = 0; j < 4; ++j) { int idx = base + j; v[j] = (idx < N) ? deg[idx] : 0; tsum += v[j]; }
    sh[tid] = tsum; __syncthreads();
    for (int off = 1; off < 256; off <<= 1) {
        int x = (tid >= off) ? sh[tid - off] : 0;
        __syncthreads();
        sh[tid] += x;
        __syncthreads();
    }
    int run = sh[tid] - tsum + bsumex[blockIdx.x];
    #pragma unroll
    for (int j = 0; j < 4; ++j) {
        int idx = base + j;
        if (idx < N) {
            row_ptr[idx] = run; cursor[idx] = run;
            dinv[idx] = rsqrtf((float)(v[j] + 1));
        }
        run += v[j];
    }
    if (blockIdx.x == 0 && tid == 0) row_ptr[N] = Etot;
}

// store (src, dinv[src]) per edge, CSR-ordered by dst
__global__ void scatter_kernel(const int* __restrict__ src, const int* __restrict__ dst,
                               const float* __restrict__ dinv,
                               int* __restrict__ cursor, uint2* __restrict__ esw, int E) {
    int i = blockIdx.x * blockDim.x + threadIdx.x;
    if (i < E) {
        int d = dst[i];
        int s = src[i];
        int pos = atomicAdd(&cursor[d], 1);
        esw[pos] = make_uint2((unsigned)s, __float_as_uint(dinv[s]));
    }
}

// ---------------- W pre-split into fragment-native layout (K=128) ----------
__global__ void wsplit_kernel(const float* __restrict__ W, ushort* __restrict__ Wh,
                              ushort* __restrict__ Wl, int FO) {
    int t = blockIdx.x * 256 + threadIdx.x;
    if (t >= 128 * FO) return;
    int j   = t & 7;
    int ci  = (t >> 3) & 127;
    int rest = t >> 10;
    int kg  = rest & 15;
    int cb  = rest >> 4;
    float w = W[(size_t)(kg * 8 + j) * FO + cb * 128 + ci];
    ushort h, l; split2(w, h, l);
    Wh[t] = h; Wl[t] = l;
}

// ---------------- actsplit: X(N x 128) -> bnrelu -> split -> blob ----------
// BN params computed inline from raw sums (csum/csq) when ACT.
template<bool ACT>
__global__ __launch_bounds__(256)
void actsplit_kernel(const float* __restrict__ X, char* __restrict__ A2,
                     const float* __restrict__ csum, const float* __restrict__ csq,
                     const float* __restrict__ g, const float* __restrict__ be,
                     float invN, int nrows)
{
    int t = blockIdx.x * 256 + threadIdx.x;
    int r = t & 127;
    int kg = (t >> 7) & 3;
    int kstep = (t >> 9) & 3;
    int rowtile = t >> 11;
    int gr = rowtile * 128 + r;
    int k = kstep * 32 + kg * 8;
    float4 v0 = make_float4(0.f, 0.f, 0.f, 0.f), v1 = v0;
    if (gr < nrows) {
        v0 = *(const float4*)&X[(size_t)gr * 128 + k];
        v1 = *(const float4*)&X[(size_t)gr * 128 + k + 4];
        if (ACT) {
            float4 s0 = *(const float4*)&csum[k], s1 = *(const float4*)&csum[k + 4];
            float4 q0 = *(const float4*)&csq[k],  q1 = *(const float4*)&csq[k + 4];
            float4 g0 = *(const float4*)&g[k],    g1v = *(const float4*)&g[k + 4];
            float4 b0 = *(const float4*)&be[k],   b1 = *(const float4*)&be[k + 4];
            #define BN1(vv, ss, qq, gg, bb) { \
                float mean = (ss) * invN; \
                float var = (qq) * invN - mean * mean; \
                float sc = (gg) * rsqrtf(var + 1e-5f); \
                (vv) = fmaxf(fmaf((vv), sc, (bb) - mean * sc), 0.f); }
            BN1(v0.x, s0.x, q0.x, g0.x, b0.x) BN1(v0.y, s0.y, q0.y, g0.y, b0.y)
            BN1(v0.z, s0.z, q0.z, g0.z, b0.z) BN1(v0.w, s0.w, q0.w, g0.w, b0.w)
            BN1(v1.x, s1.x, q1.x, g1v.x, b1.x) BN1(v1.y, s1.y, q1.y, g1v.y, b1.y)
            BN1(v1.z, s1.z, q1.z, g1v.z, b1.z) BN1(v1.w, s1.w, q1.w, g1v.w, b1.w)
            #undef BN1
        }
    }
    union { uint4 u; ushort s[8]; } ph, pl;
    split2(v0.x, ph.s[0], pl.s[0]); split2(v0.y, ph.s[1], pl.s[1]);
    split2(v0.z, ph.s[2], pl.s[2]); split2(v0.w, ph.s[3], pl.s[3]);
    split2(v1.x, ph.s[4], pl.s[4]); split2(v1.y, ph.s[5], pl.s[5]);
    split2(v1.z, ph.s[6], pl.s[6]); split2(v1.w, ph.s[7], pl.s[7]);
    char* base = A2 + ((size_t)(rowtile * 4 + kstep) * 16384) + kg * 2048 + r * 16;
    *(uint4*)base          = ph.u;
    *(uint4*)(base + 8192) = pl.u;
}

// ---------------- GEMM: C[nrows][128] (+)= A2blob @ W2[cbW] ----------------
// Prefetch-all: 64KB blob staged via 16 global_load_lds per thread, ONE barrier,
// then 4 ksteps of pure LDS+MFMA. Optional fused column stats in epilogue.
template<bool ACC, bool STATS>
__global__ __launch_bounds__(256)
void gemm_mfma_kernel(const char* __restrict__ A2, const ushort* __restrict__ W2h,
                      const ushort* __restrict__ W2l, float* __restrict__ C,
                      int nrows, int cbW, float* __restrict__ csum, float* __restrict__ csq)
{
    __shared__ char lds[65536];
    const int tid  = threadIdx.x;
    const int lane = tid & 63;
    const int wid  = tid >> 6;
    const int wm   = wid & 1, wn = wid >> 1;
    const int row0 = blockIdx.x * 128;
    const int l15  = lane & 15;
    const int l4   = lane >> 4;

    const char* blob = A2 + (size_t)blockIdx.x * 65536;
    #pragma unroll
    for (int j = 0; j < 16; ++j) {
        int plane = wid * 16 + j;
        gload_lds16(blob + plane * 1024 + lane * 16, &lds[plane * 1024]);
    }

    f32x4 zero = {0.f, 0.f, 0.f, 0.f};
    f32x4 acc[4][4];
    #pragma unroll
    for (int m = 0; m < 4; ++m)
        #pragma unroll
        for (int n = 0; n < 4; ++n) acc[m][n] = zero;

    __syncthreads();   // single drain: vmcnt(0) + barrier

    #pragma unroll
    for (int kstep = 0; kstep < 4; ++kstep) {
        const int kbase = kstep * 16384;
        bf16x8 bh[4], bl[4];
        #pragma unroll
        for (int n = 0; n < 4; ++n) {
            int ci = wn * 64 + n * 16 + l15;
            size_t off = (((size_t)(cbW * 16 + kstep * 4 + l4)) * 128 + ci) * 8;
            bh[n] = *(const bf16x8*)&W2h[off];
            bl[n] = *(const bf16x8*)&W2l[off];
        }
        bf16x8 ah[4], al[4];
        #pragma unroll
        for (int m = 0; m < 4; ++m) {
            int o = kbase + l4 * 2048 + (wm * 64 + m * 16 + l15) * 16;
            ah[m] = *(const bf16x8*)&lds[o];
            al[m] = *(const bf16x8*)&lds[o + 8192];
        }
        #pragma unroll
        for (int m = 0; m < 4; ++m)
            #pragma unroll
            for (int n = 0; n < 4; ++n) {
                acc[m][n] = __builtin_amdgcn_mfma_f32_16x16x32_bf16(ah[m], bh[n], acc[m][n], 0, 0, 0);
                acc[m][n] = __builtin_amdgcn_mfma_f32_16x16x32_bf16(ah[m], bl[n], acc[m][n], 0, 0, 0);
                acc[m][n] = __builtin_amdgcn_mfma_f32_16x16x32_bf16(al[m], bh[n], acc[m][n], 0, 0, 0);
            }
    }

    // epilogue: row = (lane>>4)*4 + reg, col = lane&15 within fragment
    float s[4] = {0.f, 0.f, 0.f, 0.f}, q[4] = {0.f, 0.f, 0.f, 0.f};
    #pragma unroll
    for (int m = 0; m < 4; ++m) {
        int rbase = row0 + wm * 64 + m * 16 + l4 * 4;
        #pragma unroll
        for (int r = 0; r < 4; ++r) {
            int gr = rbase + r;
            if (gr < nrows) {
                #pragma unroll
                for (int n = 0; n < 4; ++n) {
                    int gc = wn * 64 + n * 16 + l15;
                    size_t idx = (size_t)gr * 128 + gc;
                    float v = acc[m][n][r];
                    if (ACC) v += C[idx];
                    C[idx] = v;
                    if (STATS) { s[n] += v; q[n] += v * v; }
                }
            }
        }
    }
    if (STATS) {
        #pragma unroll
        for (int n = 0; n < 4; ++n) {
            s[n] += __shfl_xor(s[n], 16); s[n] += __shfl_xor(s[n], 32);
            q[n] += __shfl_xor(q[n], 16); q[n] += __shfl_xor(q[n], 32);
        }
        if (l4 == 0) {
            #pragma unroll
            for (int n = 0; n < 4; ++n) {
                int col = wn * 64 + n * 16 + l15;
                atomicAdd(&csum[col], s[n]);
                atomicAdd(&csq[col], q[n]);
            }
        }
    }
}

// ---------------- edge aggregation + fused column stats ----------------
// A[i] = dinv[i] * sum_e w_e * T[src_e] + dinv[i]^2 * T[i]
__global__ void agg_kernel(const float* __restrict__ T, float* __restrict__ Aout,
                           const float* __restrict__ dinv,
                           const int* __restrict__ row_ptr, const uint2* __restrict__ esw,
                           int nrows, float* __restrict__ csum, float* __restrict__ csq)
{
    __shared__ float sred[1024];
    int lane = threadIdx.x & 63;
    int wid = threadIdx.x >> 6;
    int gw = (blockIdx.x * blockDim.x + threadIdx.x) >> 6;
    int nw = (gridDim.x * blockDim.x) >> 6;
    int c = lane * 2;
    float sx = 0.f, sy = 0.f, qx = 0.f, qy = 0.f;
    for (int i = gw; i < nrows; i += nw) {
        float di = dinv[i];
        int e0 = __builtin_amdgcn_readfirstlane(row_ptr[i]);
        int e1 = __builtin_amdgcn_readfirstlane(row_ptr[i + 1]);
        float ax0 = 0.f, ay0 = 0.f, ax1 = 0.f, ay1 = 0.f;
        int e = e0;
        int n8 = e0 + ((e1 - e0) & ~7);
        for (; e < n8; e += 8) {
            uint2 p[8];
            #pragma unroll
            for (int j = 0; j < 8; ++j) p[j] = esw[e + j];
            float2 v[8];
            #pragma unroll
            for (int j = 0; j < 8; ++j) v[j] = *(const float2*)&T[((size_t)p[j].x << 7) + c];
            #pragma unroll
            for (int j = 0; j < 8; ++j) {
                float w = __uint_as_float(p[j].y);
                if (j & 1) { ax1 = fmaf(w, v[j].x, ax1); ay1 = fmaf(w, v[j].y, ay1); }
                else       { ax0 = fmaf(w, v[j].x, ax0); ay0 = fmaf(w, v[j].y, ay0); }
            }
        }
        for (; e < e1; ++e) {
            uint2 p = esw[e];
            float w = __uint_as_float(p.y);
            float2 v = *(const float2*)&T[((size_t)p.x << 7) + c];
            ax0 = fmaf(w, v.x, ax0); ay0 = fmaf(w, v.y, ay0);
        }
        float ax = ax0 + ax1, ay = ay0 + ay1;
        float2 self = *(const float2*)&T[((size_t)i << 7) + c];
        float2 o;
        o.x = fmaf(di, ax, di * di * self.x);
        o.y = fmaf(di, ay, di * di * self.y);
        *(float2*)&Aout[((size_t)i << 7) + c] = o;
        sx += o.x; sy += o.y;
        qx += o.x * o.x; qy += o.y * o.y;
    }
    // block-level stat reduce: 4 waves share the same 2-col-per-lane pattern
    int si = (wid * 64 + lane) * 4;
    sred[si] = sx; sred[si + 1] = sy; sred[si + 2] = qx; sred[si + 3] = qy;
    __syncthreads();
    if (wid == 0) {
        float a0 = 0.f, a1 = 0.f, a2 = 0.f, a3 = 0.f;
        #pragma unroll
        for (int w = 0; w < 4; ++w) {
            int b = (w * 64 + lane) * 4;
            a0 += sred[b]; a1 += sred[b + 1]; a2 += sred[b + 2]; a3 += sred[b + 3];
        }
        atomicAdd(&csum[c], a0);     atomicAdd(&csum[c + 1], a1);
        atomicAdd(&csq[c], a2);      atomicAdd(&csq[c + 1], a3);
    }
}

// ---------------- final: sigmoid( dot(bnrelu(A[i]), Wo) + bo ) --------------
__global__ void final_kernel(const float* __restrict__ A, const float* __restrict__ Wo,
                             const float* __restrict__ bo,
                             const float* __restrict__ csum, const float* __restrict__ csq,
                             const float* __restrict__ g, const float* __restrict__ be,
                             float invN, float* __restrict__ out, int nrows)
{
    int gw = (blockIdx.x * blockDim.x + threadIdx.x) >> 6;
    int lane = threadIdx.x & 63;
    int nw = (gridDim.x * blockDim.x) >> 6;
    int c = lane * 2;
    float2 w = *(const float2*)&Wo[c];
    float2 sm = *(const float2*)&csum[c];
    float2 sq = *(const float2*)&csq[c];
    float2 gg = *(const float2*)&g[c];
    float2 bb = *(const float2*)&be[c];
    float mean0 = sm.x * invN, mean1 = sm.y * invN;
    float sc0 = gg.x * rsqrtf(sq.x * invN - mean0 * mean0 + 1e-5f);
    float sc1 = gg.y * rsqrtf(sq.y * invN - mean1 * mean1 + 1e-5f);
    float sf0 = bb.x - mean0 * sc0;
    float sf1 = bb.y - mean1 * sc1;
    float bias = bo[0];
    for (int i = gw; i < nrows; i += nw) {
        float2 v = *(const float2*)&A[(size_t)i * 128 + c];
        float x = fmaxf(fmaf(v.x, sc0, sf0), 0.f) * w.x
                + fmaxf(fmaf(v.y, sc1, sf1), 0.f) * w.y;
        #pragma unroll
        for (int off = 32; off > 0; off >>= 1) x += __shfl_down(x, off);
        if (lane == 0) out[i] = 1.f / (1.f + expf(-(x + bias)));
    }
}

extern "C" void kernel_launch(void* const* d_in, const int* in_sizes, int n_in,
                              void* d_out, int out_size, void* d_ws, size_t ws_size,
                              hipStream_t stream)
{
    const float* x   = (const float*)d_in[0];
    const int* ei    = (const int*)d_in[1];
    const float* Wg1 = (const float*)d_in[2];
    const float* g1  = (const float*)d_in[4];
    const float* be1 = (const float*)d_in[5];
    const float* Wg2 = (const float*)d_in[6];
    const float* g2  = (const float*)d_in[8];
    const float* be2 = (const float*)d_in[9];
    const float* Wm1 = (const float*)d_in[10];
    const float* g3  = (const float*)d_in[12];
    const float* be3 = (const float*)d_in[13];
    const float* Wm2 = (const float*)d_in[14];
    const float* g4  = (const float*)d_in[16];
    const float* be4 = (const float*)d_in[17];
    const float* Wo  = (const float*)d_in[18];
    const float* bo  = (const float*)d_in[19];

    const int N = in_sizes[0] / 128;
    const int E = in_sizes[1] / 2;
    const int* srcv = ei;
    const int* dstv = ei + E;
    const int rowtiles = (N + 127) / 128;
    const size_t blobsz = (size_t)rowtiles * 4 * 16384;

    char* p = (char*)d_ws;
    auto alloc = [&](size_t bytes) { void* r = (void*)p; p += (bytes + 255) & ~(size_t)255; return r; };
    float* buf1    = (float*)alloc((size_t)N * 128 * 4);
    char*  buf2    = (char*)alloc(blobsz);
    char*  buf3    = (char*)alloc(blobsz);
    const size_t degB = ((size_t)N * 4 + 15) & ~(size_t)15;
    char*  zreg    = (char*)alloc(degB + 5 * 1024);       // deg + 5 stat buffers, one memset
    int*   deg     = (int*)zreg;
    float* SB      = (float*)(zreg + degB);               // 5 x (csum[128]+csq[128])
    float* dinv    = (float*)alloc((size_t)N * 4);
    int*   row_ptr = (int*)alloc((size_t)(N + 1) * 4);
    int*   cursor  = (int*)alloc((size_t)N * 4);
    uint2* esw     = (uint2*)alloc((size_t)(E + 8) * 8);
    int*   bsum    = (int*)alloc(4096);
    ushort* W2h    = (ushort*)alloc(32768 * 2);
    ushort* W2l    = (ushort*)alloc(32768 * 2);

    float* S1 = SB,        *S1q = SB + 128;
    float* S2 = SB + 256,  *S2q = SB + 384;
    float* S3a = SB + 512, *S3aq = SB + 640;
    float* S3b = SB + 768, *S3bq = SB + 896;
    float* S4 = SB + 1024, *S4q = SB + 1152;

    float* Abuf = (float*)buf2;
    float* C4   = (float*)buf3;
    const float invN = 1.f / (float)N;
    const int as_blocks = rowtiles * 8;

    // --- CSR build ---
    (void)hipMemsetAsync(zreg, 0, degB + 5 * 1024, stream);
    degree_kernel<<<(E + 255) / 256, 256, 0, stream>>>(dstv, deg, E);
    int nb = (N + 1023) / 1024;
    blocksum_kernel<<<nb, 256, 0, stream>>>(deg, bsum, N);
    scan_bsum_kernel<<<1, 64, 0, stream>>>(bsum, nb);
    scanwrite_kernel<<<nb, 256, 0, stream>>>(deg, bsum, row_ptr, cursor, dinv, N, E);
    scatter_kernel<<<(E + 255) / 256, 256, 0, stream>>>(srcv, dstv, dinv, cursor, esw, E);

    dim3 gg(rowtiles, 1);

    // --- L1 ---
    wsplit_kernel<<<64, 256, 0, stream>>>(Wg1, W2h, W2l, 128);
    actsplit_kernel<false><<<as_blocks, 256, 0, stream>>>(x, buf3, nullptr, nullptr, nullptr, nullptr, invN, N);
    gemm_mfma_kernel<false, false><<<gg, 256, 0, stream>>>(buf3, W2h, W2l, buf1, N, 0, nullptr, nullptr);
    agg_kernel<<<2048, 256, 0, stream>>>(buf1, Abuf, dinv, row_ptr, esw, N, S1, S1q);

    // --- L2 ---
    wsplit_kernel<<<64, 256, 0, stream>>>(Wg2, W2h, W2l, 128);
    actsplit_kernel<true><<<as_blocks, 256, 0, stream>>>(Abuf, buf3, S1, S1q, g1, be1, invN, N);
    gemm_mfma_kernel<false, false><<<gg, 256, 0, stream>>>(buf3, W2h, W2l, buf1, N, 0, nullptr, nullptr);
    agg_kernel<<<2048, 256, 0, stream>>>(buf1, Abuf, dinv, row_ptr, esw, N, S2, S2q);

    // --- L3 (two column halves, stats fused in GEMM epilogue) ---
    actsplit_kernel<true><<<as_blocks, 256, 0, stream>>>(Abuf, buf3, S2, S2q, g2, be2, invN, N);
    wsplit_kernel<<<128, 256, 0, stream>>>(Wm1, W2h, W2l, 256);
    gemm_mfma_kernel<false, true><<<gg, 256, 0, stream>>>(buf3, W2h, W2l, buf1, N, 0, S3a, S3aq);
    actsplit_kernel<true><<<as_blocks, 256, 0, stream>>>(buf1, buf2, S3a, S3aq, g3, be3, invN, N);
    gemm_mfma_kernel<false, true><<<gg, 256, 0, stream>>>(buf3, W2h, W2l, buf1, N, 1, S3b, S3bq);

    // --- L4 (two K halves; stats on final ACC epilogue) ---
    wsplit_kernel<<<64, 256, 0, stream>>>(Wm2, W2h, W2l, 128);
    gemm_mfma_kernel<false, false><<<gg, 256, 0, stream>>>(buf2, W2h, W2l, C4, N, 0, nullptr, nullptr);
    actsplit_kernel<true><<<as_blocks, 256, 0, stream>>>(buf1, buf2, S3b, S3bq, g3 + 128, be3 + 128, invN, N);
    wsplit_kernel<<<64, 256, 0, stream>>>(Wm2 + 128 * 128, W2h, W2l, 128);
    gemm_mfma_kernel<true, true><<<gg, 256, 0, stream>>>(buf2, W2h, W2l, C4, N, 0, S4, S4q);

    // --- output ---
    final_kernel<<<1024, 256, 0, stream>>>(C4, Wo, bo, S4, S4q, g4, be4, invN, (float*)d_out, N);
}

// Round 8
// 1051.486 us; speedup vs baseline: 1.0169x; 1.0079x over previous
//
#include <hip/hip_runtime.h>
#include <hip/hip_bf16.h>
#include <math.h>

// ---------------------------------------------------------------------------
// GCN classifier pipeline, split-bf16 MFMA GEMMs, blob-staged A (prefetch-all),
// fused column-stats (in agg + GEMM epilogues), BN params computed inline in
// consumers. 3 rotating 51MB buffers. Single merged weight-split dispatch.
//   L1: t = x @ Wg1         ; a = agg(t)+stats(S1)
//   L2: t = bnrelu1(a)@Wg2  ; a = agg(t)+stats(S2)
//   L3: th = bnrelu2(a)@Wm1[:,h*128:+128]  (+stats S3a/S3b in epilogue)
//   L4: c4 = sum_h bnrelu3h(th)@Wm2[h*128:+128,:]  (+stats S4 on final ACC)
//   out = sigmoid( dot(bnrelu4(c4), Wo) + bo )
// ---------------------------------------------------------------------------

typedef __attribute__((ext_vector_type(8))) short bf16x8;
typedef __attribute__((ext_vector_type(4))) float f32x4;

// trunc-hi + rne-lo split: residual ~2^-17 relative
__device__ inline void split2(float x, ushort& h, ushort& l) {
    unsigned u = __float_as_uint(x);
    h = (ushort)(u >> 16);
    float hb = __uint_as_float(u & 0xFFFF0000u);
    float lo = x - hb;
    unsigned b = __float_as_uint(lo);
    l = (ushort)((b + 0x7FFFu + ((b >> 16) & 1u)) >> 16);
}

__device__ inline void gload_lds16(const void* g, void* l) {
#if defined(__HIP_DEVICE_COMPILE__)
    __builtin_amdgcn_global_load_lds(
        (const __attribute__((address_space(1))) unsigned int*)g,
        (__attribute__((address_space(3))) unsigned int*)l, 16, 0, 0);
#endif
}

// ---------------- CSR build ----------------
__global__ void degree_kernel(const int* __restrict__ dst, int* __restrict__ deg, int E) {
    int i = blockIdx.x * blockDim.x + threadIdx.x;
    if (i < E) atomicAdd(&deg[dst[i]], 1);
}

__global__ void blocksum_kernel(const int* __restrict__ deg, int* __restrict__ bsum, int N) {
    __shared__ int sh[256];
    int tid = threadIdx.x;
    int base = blockIdx.x * 1024 + tid * 4;
    int s = 0;
    #pragma unroll
    for (int j = 0; j < 4; ++j) { int idx = base + j; if (idx < N) s += deg[idx]; }
    sh[tid] = s; __syncthreads();
    for (int off = 128; off > 0; off >>= 1) {
        if (tid < off) sh[tid] += sh[tid + off];
        __syncthreads();
    }
    if (tid == 0) bsum[blockIdx.x] = sh[0];
}

__global__ void scan_bsum_kernel(int* bsum, int nb) {
    if (threadIdx.x == 0 && blockIdx.x == 0) {
        int run = 0;
        for (int i = 0; i < nb; ++i) { int v = bsum[i]; bsum[i] = run; run += v; }
    }
}

// exclusive scan of deg -> row_ptr/cursor; also dinv = rsqrt(deg+1)
__global__ void scanwrite_kernel(const int* __restrict__ deg, const int* __restrict__ bsumex,
                                 int* __restrict__ row_ptr, int* __restrict__ cursor,
                                 float* __restrict__ dinv, int N, int Etot) {
    __shared__ int sh[256];
    int tid = threadIdx.x;
    int base = blockIdx.x * 1024 + tid * 4;
    int v[4]; int tsum = 0;
    #pragma unroll
    for (int j = 0; j < 4; ++j) { int idx = base + j; v[j] = (idx < N) ? deg[idx] : 0; tsum += v[j]; }
    sh[tid] = tsum; __syncthreads();
    for (int off = 1; off < 256; off <<= 1) {
        int x = (tid >= off) ? sh[tid - off] : 0;
        __syncthreads();
        sh[tid] += x;
        __syncthreads();
    }
    int run = sh[tid] - tsum + bsumex[blockIdx.x];
    #pragma unroll
    for (int j = 0; j < 4; ++j) {
        int idx = base + j;
        if (idx < N) {
            row_ptr[idx] = run; cursor[idx] = run;
            dinv[idx] = rsqrtf((float)(v[j] + 1));
        }
        run += v[j];
    }
    if (blockIdx.x == 0 && tid == 0) row_ptr[N] = Etot;
}

// store (src, dinv[src]) per edge, CSR-ordered by dst
__global__ void scatter_kernel(const int* __restrict__ src, const int* __restrict__ dst,
                               const float* __restrict__ dinv,
                               int* __restrict__ cursor, uint2* __restrict__ esw, int E) {
    int i = blockIdx.x * blockDim.x + threadIdx.x;
    if (i < E) {
        int d = dst[i];
        int s = src[i];
        int pos = atomicAdd(&cursor[d], 1);
        esw[pos] = make_uint2((unsigned)s, __float_as_uint(dinv[s]));
    }
}

// ---------------- merged W pre-split: 6 fragment blocks of 16384 -----------
// block: 0=Wg1, 1=Wg2, 2=Wm1 cols0, 3=Wm1 cols1, 4=Wm2 rows0, 5=Wm2 rows1
// layout within block: ((kg)*128+ci)*8+j = split(W[kg*8+j][cb*128+ci])
__global__ void wsplit_all_kernel(const float* __restrict__ Wg1, const float* __restrict__ Wg2,
                                  const float* __restrict__ Wm1, const float* __restrict__ Wm2,
                                  ushort* __restrict__ Wh, ushort* __restrict__ Wl) {
    int t = blockIdx.x * 256 + threadIdx.x;     // 6*16384 = 98304 threads
    int which = t >> 14;
    int inner = t & 16383;
    int j  = inner & 7;
    int ci = (inner >> 3) & 127;
    int kg = (inner >> 10) & 15;
    const float* W; int FO; int cb;
    switch (which) {
        case 0:  W = Wg1;             FO = 128; cb = 0; break;
        case 1:  W = Wg2;             FO = 128; cb = 0; break;
        case 2:  W = Wm1;             FO = 256; cb = 0; break;
        case 3:  W = Wm1;             FO = 256; cb = 1; break;
        case 4:  W = Wm2;             FO = 128; cb = 0; break;
        default: W = Wm2 + 128 * 128; FO = 128; cb = 0; break;
    }
    float w = W[(size_t)(kg * 8 + j) * FO + cb * 128 + ci];
    ushort h, l; split2(w, h, l);
    Wh[t] = h; Wl[t] = l;
}

// ---------------- actsplit: X(N x 128) -> bnrelu -> split -> blob ----------
// BN params computed inline from raw sums (csum/csq) when ACT.
template<bool ACT>
__global__ __launch_bounds__(256)
void actsplit_kernel(const float* __restrict__ X, char* __restrict__ A2,
                     const float* __restrict__ csum, const float* __restrict__ csq,
                     const float* __restrict__ g, const float* __restrict__ be,
                     float invN, int nrows)
{
    int t = blockIdx.x * 256 + threadIdx.x;
    int r = t & 127;
    int kg = (t >> 7) & 3;
    int kstep = (t >> 9) & 3;
    int rowtile = t >> 11;
    int gr = rowtile * 128 + r;
    int k = kstep * 32 + kg * 8;
    float4 v0 = make_float4(0.f, 0.f, 0.f, 0.f), v1 = v0;
    if (gr < nrows) {
        v0 = *(const float4*)&X[(size_t)gr * 128 + k];
        v1 = *(const float4*)&X[(size_t)gr * 128 + k + 4];
        if (ACT) {
            float4 s0 = *(const float4*)&csum[k], s1 = *(const float4*)&csum[k + 4];
            float4 q0 = *(const float4*)&csq[k],  q1 = *(const float4*)&csq[k + 4];
            float4 g0 = *(const float4*)&g[k],    g1v = *(const float4*)&g[k + 4];
            float4 b0 = *(const float4*)&be[k],   b1 = *(const float4*)&be[k + 4];
            #define BN1(vv, ss, qq, gg, bb) { \
                float mean = (ss) * invN; \
                float var = (qq) * invN - mean * mean; \
                float sc = (gg) * rsqrtf(var + 1e-5f); \
                (vv) = fmaxf(fmaf((vv), sc, (bb) - mean * sc), 0.f); }
            BN1(v0.x, s0.x, q0.x, g0.x, b0.x) BN1(v0.y, s0.y, q0.y, g0.y, b0.y)
            BN1(v0.z, s0.z, q0.z, g0.z, b0.z) BN1(v0.w, s0.w, q0.w, g0.w, b0.w)
            BN1(v1.x, s1.x, q1.x, g1v.x, b1.x) BN1(v1.y, s1.y, q1.y, g1v.y, b1.y)
            BN1(v1.z, s1.z, q1.z, g1v.z, b1.z) BN1(v1.w, s1.w, q1.w, g1v.w, b1.w)
            #undef BN1
        }
    }
    union { uint4 u; ushort s[8]; } ph, pl;
    split2(v0.x, ph.s[0], pl.s[0]); split2(v0.y, ph.s[1], pl.s[1]);
    split2(v0.z, ph.s[2], pl.s[2]); split2(v0.w, ph.s[3], pl.s[3]);
    split2(v1.x, ph.s[4], pl.s[4]); split2(v1.y, ph.s[5], pl.s[5]);
    split2(v1.z, ph.s[6], pl.s[6]); split2(v1.w, ph.s[7], pl.s[7]);
    char* base = A2 + ((size_t)(rowtile * 4 + kstep) * 16384) + kg * 2048 + r * 16;
    *(uint4*)base          = ph.u;
    *(uint4*)(base + 8192) = pl.u;
}

// ---------------- GEMM: C[nrows][128] (+)= A2blob @ W2 ----------------
// Prefetch-all: 64KB blob staged via 16 global_load_lds per thread, ONE barrier,
// then 4 ksteps of pure LDS+MFMA. Optional fused column stats in epilogue.
template<bool ACC, bool STATS>
__global__ __launch_bounds__(256)
void gemm_mfma_kernel(const char* __restrict__ A2, const ushort* __restrict__ W2h,
                      const ushort* __restrict__ W2l, float* __restrict__ C,
                      int nrows, float* __restrict__ csum, float* __restrict__ csq)
{
    __shared__ char lds[65536];
    const int tid  = threadIdx.x;
    const int lane = tid & 63;
    const int wid  = tid >> 6;
    const int wm   = wid & 1, wn = wid >> 1;
    const int row0 = blockIdx.x * 128;
    const int l15  = lane & 15;
    const int l4   = lane >> 4;

    const char* blob = A2 + (size_t)blockIdx.x * 65536;
    #pragma unroll
    for (int j = 0; j < 16; ++j) {
        int plane = wid * 16 + j;
        gload_lds16(blob + plane * 1024 + lane * 16, &lds[plane * 1024]);
    }

    f32x4 zero = {0.f, 0.f, 0.f, 0.f};
    f32x4 acc[4][4];
    #pragma unroll
    for (int m = 0; m < 4; ++m)
        #pragma unroll
        for (int n = 0; n < 4; ++n) acc[m][n] = zero;

    __syncthreads();   // single drain: vmcnt(0) + barrier

    #pragma unroll
    for (int kstep = 0; kstep < 4; ++kstep) {
        const int kbase = kstep * 16384;
        bf16x8 bh[4], bl[4];
        #pragma unroll
        for (int n = 0; n < 4; ++n) {
            int ci = wn * 64 + n * 16 + l15;
            size_t off = (((size_t)(kstep * 4 + l4)) * 128 + ci) * 8;
            bh[n] = *(const bf16x8*)&W2h[off];
            bl[n] = *(const bf16x8*)&W2l[off];
        }
        bf16x8 ah[4], al[4];
        #pragma unroll
        for (int m = 0; m < 4; ++m) {
            int o = kbase + l4 * 2048 + (wm * 64 + m * 16 + l15) * 16;
            ah[m] = *(const bf16x8*)&lds[o];
            al[m] = *(const bf16x8*)&lds[o + 8192];
        }
        #pragma unroll
        for (int m = 0; m < 4; ++m)
            #pragma unroll
            for (int n = 0; n < 4; ++n) {
                acc[m][n] = __builtin_amdgcn_mfma_f32_16x16x32_bf16(ah[m], bh[n], acc[m][n], 0, 0, 0);
                acc[m][n] = __builtin_amdgcn_mfma_f32_16x16x32_bf16(ah[m], bl[n], acc[m][n], 0, 0, 0);
                acc[m][n] = __builtin_amdgcn_mfma_f32_16x16x32_bf16(al[m], bh[n], acc[m][n], 0, 0, 0);
            }
    }

    // epilogue: row = (lane>>4)*4 + reg, col = lane&15 within fragment
    float s[4] = {0.f, 0.f, 0.f, 0.f}, q[4] = {0.f, 0.f, 0.f, 0.f};
    #pragma unroll
    for (int m = 0; m < 4; ++m) {
        int rbase = row0 + wm * 64 + m * 16 + l4 * 4;
        #pragma unroll
        for (int r = 0; r < 4; ++r) {
            int gr = rbase + r;
            if (gr < nrows) {
                #pragma unroll
                for (int n = 0; n < 4; ++n) {
                    int gc = wn * 64 + n * 16 + l15;
                    size_t idx = (size_t)gr * 128 + gc;
                    float v = acc[m][n][r];
                    if (ACC) v += C[idx];
                    C[idx] = v;
                    if (STATS) { s[n] += v; q[n] += v * v; }
                }
            }
        }
    }
    if (STATS) {
        #pragma unroll
        for (int n = 0; n < 4; ++n) {
            s[n] += __shfl_xor(s[n], 16); s[n] += __shfl_xor(s[n], 32);
            q[n] += __shfl_xor(q[n], 16); q[n] += __shfl_xor(q[n], 32);
        }
        if (l4 == 0) {
            #pragma unroll
            for (int n = 0; n < 4; ++n) {
                int col = wn * 64 + n * 16 + l15;
                atomicAdd(&csum[col], s[n]);
                atomicAdd(&csq[col], q[n]);
            }
        }
    }
}

// ---------------- edge aggregation + fused column stats ----------------
// A[i] = dinv[i] * sum_e w_e * T[src_e] + dinv[i]^2 * T[i]
// Inner loop: named-scalar 4-deep chunks (keeps 4 gathers in flight; the
// round-7 array-unroll variant serialized loads at VGPR=20 and regressed).
__global__ void agg_kernel(const float* __restrict__ T, float* __restrict__ Aout,
                           const float* __restrict__ dinv,
                           const int* __restrict__ row_ptr, const uint2* __restrict__ esw,
                           int nrows, float* __restrict__ csum, float* __restrict__ csq)
{
    __shared__ float sred[1024];
    int lane = threadIdx.x & 63;
    int wid = threadIdx.x >> 6;
    int gw = (blockIdx.x * blockDim.x + threadIdx.x) >> 6;
    int nw = (gridDim.x * blockDim.x) >> 6;
    int c = lane * 2;
    float sx = 0.f, sy = 0.f, qx = 0.f, qy = 0.f;
    for (int i = gw; i < nrows; i += nw) {
        float di = dinv[i];
        int e0 = __builtin_amdgcn_readfirstlane(row_ptr[i]);
        int e1 = __builtin_amdgcn_readfirstlane(row_ptr[i + 1]);
        float ax0 = 0.f, ay0 = 0.f, ax1 = 0.f, ay1 = 0.f;
        int e = e0;
        int eq = e0 + ((e1 - e0) & ~3);
        for (; e < eq; e += 4) {
            uint2 p0 = esw[e],     p1 = esw[e + 1];
            uint2 p2 = esw[e + 2], p3 = esw[e + 3];
            float2 v0 = *(const float2*)&T[((size_t)p0.x << 7) + c];
            float2 v1 = *(const float2*)&T[((size_t)p1.x << 7) + c];
            float2 v2 = *(const float2*)&T[((size_t)p2.x << 7) + c];
            float2 v3 = *(const float2*)&T[((size_t)p3.x << 7) + c];
            float w0 = __uint_as_float(p0.y), w1 = __uint_as_float(p1.y);
            float w2 = __uint_as_float(p2.y), w3 = __uint_as_float(p3.y);
            ax0 = fmaf(w0, v0.x, ax0); ay0 = fmaf(w0, v0.y, ay0);
            ax1 = fmaf(w1, v1.x, ax1); ay1 = fmaf(w1, v1.y, ay1);
            ax0 = fmaf(w2, v2.x, ax0); ay0 = fmaf(w2, v2.y, ay0);
            ax1 = fmaf(w3, v3.x, ax1); ay1 = fmaf(w3, v3.y, ay1);
        }
        for (; e < e1; ++e) {
            uint2 p = esw[e];
            float w = __uint_as_float(p.y);
            float2 v = *(const float2*)&T[((size_t)p.x << 7) + c];
            ax0 = fmaf(w, v.x, ax0); ay0 = fmaf(w, v.y, ay0);
        }
        float ax = ax0 + ax1, ay = ay0 + ay1;
        float2 self = *(const float2*)&T[((size_t)i << 7) + c];
        float2 o;
        o.x = fmaf(di, ax, di * di * self.x);
        o.y = fmaf(di, ay, di * di * self.y);
        *(float2*)&Aout[((size_t)i << 7) + c] = o;
        sx += o.x; sy += o.y;
        qx += o.x * o.x; qy += o.y * o.y;
    }
    // block-level stat reduce: 4 waves share the same 2-col-per-lane pattern
    int si = (wid * 64 + lane) * 4;
    sred[si] = sx; sred[si + 1] = sy; sred[si + 2] = qx; sred[si + 3] = qy;
    __syncthreads();
    if (wid == 0) {
        float a0 = 0.f, a1 = 0.f, a2 = 0.f, a3 = 0.f;
        #pragma unroll
        for (int w = 0; w < 4; ++w) {
            int b = (w * 64 + lane) * 4;
            a0 += sred[b]; a1 += sred[b + 1]; a2 += sred[b + 2]; a3 += sred[b + 3];
        }
        atomicAdd(&csum[c], a0);     atomicAdd(&csum[c + 1], a1);
        atomicAdd(&csq[c], a2);      atomicAdd(&csq[c + 1], a3);
    }
}

// ---------------- final: sigmoid( dot(bnrelu(A[i]), Wo) + bo ) --------------
__global__ void final_kernel(const float* __restrict__ A, const float* __restrict__ Wo,
                             const float* __restrict__ bo,
                             const float* __restrict__ csum, const float* __restrict__ csq,
                             const float* __restrict__ g, const float* __restrict__ be,
                             float invN, float* __restrict__ out, int nrows)
{
    int gw = (blockIdx.x * blockDim.x + threadIdx.x) >> 6;
    int lane = threadIdx.x & 63;
    int nw = (gridDim.x * blockDim.x) >> 6;
    int c = lane * 2;
    float2 w = *(const float2*)&Wo[c];
    float2 sm = *(const float2*)&csum[c];
    float2 sq = *(const float2*)&csq[c];
    float2 gg = *(const float2*)&g[c];
    float2 bb = *(const float2*)&be[c];
    float mean0 = sm.x * invN, mean1 = sm.y * invN;
    float sc0 = gg.x * rsqrtf(sq.x * invN - mean0 * mean0 + 1e-5f);
    float sc1 = gg.y * rsqrtf(sq.y * invN - mean1 * mean1 + 1e-5f);
    float sf0 = bb.x - mean0 * sc0;
    float sf1 = bb.y - mean1 * sc1;
    float bias = bo[0];
    for (int i = gw; i < nrows; i += nw) {
        float2 v = *(const float2*)&A[(size_t)i * 128 + c];
        float x = fmaxf(fmaf(v.x, sc0, sf0), 0.f) * w.x
                + fmaxf(fmaf(v.y, sc1, sf1), 0.f) * w.y;
        #pragma unroll
        for (int off = 32; off > 0; off >>= 1) x += __shfl_down(x, off);
        if (lane == 0) out[i] = 1.f / (1.f + expf(-(x + bias)));
    }
}

extern "C" void kernel_launch(void* const* d_in, const int* in_sizes, int n_in,
                              void* d_out, int out_size, void* d_ws, size_t ws_size,
                              hipStream_t stream)
{
    const float* x   = (const float*)d_in[0];
    const int* ei    = (const int*)d_in[1];
    const float* Wg1 = (const float*)d_in[2];
    const float* g1  = (const float*)d_in[4];
    const float* be1 = (const float*)d_in[5];
    const float* Wg2 = (const float*)d_in[6];
    const float* g2  = (const float*)d_in[8];
    const float* be2 = (const float*)d_in[9];
    const float* Wm1 = (const float*)d_in[10];
    const float* g3  = (const float*)d_in[12];
    const float* be3 = (const float*)d_in[13];
    const float* Wm2 = (const float*)d_in[14];
    const float* g4  = (const float*)d_in[16];
    const float* be4 = (const float*)d_in[17];
    const float* Wo  = (const float*)d_in[18];
    const float* bo  = (const float*)d_in[19];

    const int N = in_sizes[0] / 128;
    const int E = in_sizes[1] / 2;
    const int* srcv = ei;
    const int* dstv = ei + E;
    const int rowtiles = (N + 127) / 128;
    const size_t blobsz = (size_t)rowtiles * 4 * 16384;

    char* p = (char*)d_ws;
    auto alloc = [&](size_t bytes) { void* r = (void*)p; p += (bytes + 255) & ~(size_t)255; return r; };
    float* buf1    = (float*)alloc((size_t)N * 128 * 4);
    char*  buf2    = (char*)alloc(blobsz);
    char*  buf3    = (char*)alloc(blobsz);
    const size_t degB = ((size_t)N * 4 + 15) & ~(size_t)15;
    char*  zreg    = (char*)alloc(degB + 5 * 1024);       // deg + 5 stat buffers, one memset
    int*   deg     = (int*)zreg;
    float* SB      = (float*)(zreg + degB);               // 5 x (csum[128]+csq[128])
    float* dinv    = (float*)alloc((size_t)N * 4);
    int*   row_ptr = (int*)alloc((size_t)(N + 1) * 4);
    int*   cursor  = (int*)alloc((size_t)N * 4);
    uint2* esw     = (uint2*)alloc((size_t)(E + 8) * 8);
    int*   bsum    = (int*)alloc(4096);
    ushort* W2h    = (ushort*)alloc(98304 * 2);           // 6 x 16384 fragment blocks
    ushort* W2l    = (ushort*)alloc(98304 * 2);

    float* S1 = SB,        *S1q = SB + 128;
    float* S2 = SB + 256,  *S2q = SB + 384;
    float* S3a = SB + 512, *S3aq = SB + 640;
    float* S3b = SB + 768, *S3bq = SB + 896;
    float* S4 = SB + 1024, *S4q = SB + 1152;

    float* Abuf = (float*)buf2;
    float* C4   = (float*)buf3;
    const float invN = 1.f / (float)N;
    const int as_blocks = rowtiles * 8;

    // --- CSR build + merged weight split ---
    (void)hipMemsetAsync(zreg, 0, degB + 5 * 1024, stream);
    wsplit_all_kernel<<<384, 256, 0, stream>>>(Wg1, Wg2, Wm1, Wm2, W2h, W2l);
    degree_kernel<<<(E + 255) / 256, 256, 0, stream>>>(dstv, deg, E);
    int nb = (N + 1023) / 1024;
    blocksum_kernel<<<nb, 256, 0, stream>>>(deg, bsum, N);
    scan_bsum_kernel<<<1, 64, 0, stream>>>(bsum, nb);
    scanwrite_kernel<<<nb, 256, 0, stream>>>(deg, bsum, row_ptr, cursor, dinv, N, E);
    scatter_kernel<<<(E + 255) / 256, 256, 0, stream>>>(srcv, dstv, dinv, cursor, esw, E);

    dim3 gg(rowtiles, 1);

    // --- L1 ---
    actsplit_kernel<false><<<as_blocks, 256, 0, stream>>>(x, buf3, nullptr, nullptr, nullptr, nullptr, invN, N);
    gemm_mfma_kernel<false, false><<<gg, 256, 0, stream>>>(buf3, W2h, W2l, buf1, N, nullptr, nullptr);
    agg_kernel<<<2048, 256, 0, stream>>>(buf1, Abuf, dinv, row_ptr, esw, N, S1, S1q);

    // --- L2 ---
    actsplit_kernel<true><<<as_blocks, 256, 0, stream>>>(Abuf, buf3, S1, S1q, g1, be1, invN, N);
    gemm_mfma_kernel<false, false><<<gg, 256, 0, stream>>>(buf3, W2h + 16384, W2l + 16384, buf1, N, nullptr, nullptr);
    agg_kernel<<<2048, 256, 0, stream>>>(buf1, Abuf, dinv, row_ptr, esw, N, S2, S2q);

    // --- L3 (two column halves, stats fused in GEMM epilogue) ---
    actsplit_kernel<true><<<as_blocks, 256, 0, stream>>>(Abuf, buf3, S2, S2q, g2, be2, invN, N);
    gemm_mfma_kernel<false, true><<<gg, 256, 0, stream>>>(buf3, W2h + 2 * 16384, W2l + 2 * 16384, buf1, N, S3a, S3aq);
    actsplit_kernel<true><<<as_blocks, 256, 0, stream>>>(buf1, buf2, S3a, S3aq, g3, be3, invN, N);
    gemm_mfma_kernel<false, true><<<gg, 256, 0, stream>>>(buf3, W2h + 3 * 16384, W2l + 3 * 16384, buf1, N, S3b, S3bq);

    // --- L4 (two K halves; stats on final ACC epilogue) ---
    gemm_mfma_kernel<false, false><<<gg, 256, 0, stream>>>(buf2, W2h + 4 * 16384, W2l + 4 * 16384, C4, N, nullptr, nullptr);
    actsplit_kernel<true><<<as_blocks, 256, 0, stream>>>(buf1, buf2, S3b, S3bq, g3 + 128, be3 + 128, invN, N);
    gemm_mfma_kernel<true, true><<<gg, 256, 0, stream>>>(buf2, W2h + 5 * 16384, W2l + 5 * 16384, C4, N, S4, S4q);

    // --- output ---
    final_kernel<<<1024, 256, 0, stream>>>(C4, Wo, bo, S4, S4q, g4, be4, invN, (float*)d_out, N);
}